// Round 11
// baseline (23322.960 us; speedup 1.0000x reference)
//
#include <hip/hip_runtime.h>

typedef __attribute__((ext_vector_type(8))) short bhalf8;
typedef __attribute__((ext_vector_type(4))) float floatx4;

#define NSLOTS 502
#define BLOCK 768   // 12 waves = gate(3) x colhalf(2) x khalf(2)

#define AS1 __attribute__((address_space(1)))
#define AS3 __attribute__((address_space(3)))
// aux=1: sc0 (bypass L1, served by OWN-XCD L2 -- for XCD-local buffers).
// aux=0: plain cached (read-only data).
#define GLL_SC0(g, s)   __builtin_amdgcn_global_load_lds((const AS1 unsigned*)(g), (AS3 unsigned*)(s), 16, 0, 1)
#define GLL_PLAIN(g, s) __builtin_amdgcn_global_load_lds((const AS1 unsigned*)(g), (AS3 unsigned*)(s), 16, 0, 0)

__device__ __forceinline__ unsigned short f2b(float f) {
  unsigned u = __float_as_uint(f);
  return (unsigned short)((u + 0x7FFFu + ((u >> 16) & 1u)) >> 16);
}
// agent-scope (sc0|sc1): the ONLY ops used on cross-XCD buffers (both sides). Proven R3-R8.
__device__ __forceinline__ int cloadi(const int* p) {
  return __hip_atomic_load(p, __ATOMIC_RELAXED, __HIP_MEMORY_SCOPE_AGENT);
}
__device__ __forceinline__ void cstorei(int* p, int v) {
  __hip_atomic_store(p, v, __ATOMIC_RELAXED, __HIP_MEMORY_SCOPE_AGENT);
}
__device__ __forceinline__ unsigned long long cload8(const unsigned long long* p) {
  return __hip_atomic_load(p, __ATOMIC_RELAXED, __HIP_MEMORY_SCOPE_AGENT);
}
__device__ __forceinline__ void cstore8(unsigned long long* p, unsigned long long v) {
  __hip_atomic_store(p, v, __ATOMIC_RELAXED, __HIP_MEMORY_SCOPE_AGENT);
}

__global__ void prep_w(const float* __restrict__ wih, const float* __restrict__ whh,
                       unsigned short* __restrict__ wihb, unsigned short* __restrict__ whhb) {
  size_t i0 = (size_t)blockIdx.x * blockDim.x + threadIdx.x;
  size_t stride = (size_t)gridDim.x * blockDim.x;
  for (size_t i = i0; i < 6291456u; i += stride) { wihb[i] = f2b(wih[i]); whhb[i] = f2b(whh[i]); }
}

// res_output (B=64, H=1024, T=500) f32 -> xb (T, B, H) bf16 (coalesced transpose)
__global__ void prep_x(const float* __restrict__ x, unsigned short* __restrict__ xb) {
  __shared__ float tile[32][33];
  int b = blockIdx.z;
  int h0 = blockIdx.y * 32, t0 = blockIdx.x * 32;
  int tx = threadIdx.x, ty = threadIdx.y;
  #pragma unroll
  for (int i = 0; i < 32; i += 8) {
    int t = t0 + tx;
    if (t < 500) tile[ty + i][tx] = x[((size_t)b * 1024 + h0 + ty + i) * 500 + t];
  }
  __syncthreads();
  #pragma unroll
  for (int i = 0; i < 32; i += 8) {
    int t = t0 + ty + i;
    if (t < 500) xb[((size_t)t * 64 + b) * 1024 + h0 + tx] = f2b(tile[tx][ty + i]);
  }
}

// ws layout (bytes). Buffer discipline: [A] = all-agent (sc0sc1 both sides),
// [L:x] = XCD-local (plain stores by XCD x only, sc0 loads by XCD x only).
// 0       flgL0rem[32] [A]   128  flgL1rem[32] [A]   384  flgCopy[32] [A]   512 xcdcnt [A]
// 1024    h0rem[2]  x131072 [A]    (L0 -> L1 handoff)            -> 263168
// 263168  h1loc[2]  x131072 [L:1]  (L1 recurrence, XCD1-local)   -> 525312
// 525312  h0loc0[2] x131072 [L:0]  (L0 recurrence, XCD0-local)   -> 787456
// 787456  h0loc1[1] x131072 [L:1]  (L1's pulled copy of h0)      -> 918528
// --- zero region ends 918528 ---
// 918528   Wihb 12582912 -> 13501440
// 13501440 Whhb 12582912 -> 26084352
// 26084352 Xb (500*64*1024 bf16) -> 91620352

__launch_bounds__(BLOCK, 1)
__global__ void gru_main(const unsigned short* __restrict__ xb,
                         const unsigned short* __restrict__ wihb,
                         const unsigned short* __restrict__ whhb,
                         const float* __restrict__ wout,
                         const float* __restrict__ bih, const float* __restrict__ bhh,
                         const float* __restrict__ bout,
                         char* __restrict__ wsb, float* __restrict__ out) {
  int* flgL0rem = (int*)wsb;
  int* flgL1rem = (int*)(wsb + 128);
  int* flgCopy  = (int*)(wsb + 384);
  int* xcdcnt   = (int*)(wsb + 512);
  char* h0rem  = wsb + 1024;
  char* h1loc  = wsb + 263168;
  char* h0loc0 = wsb + 525312;
  char* h0loc1 = wsb + 787456;

  const int tid = threadIdx.x;
  const int w = tid >> 6;
  const int l = tid & 63;
  const int l15 = l & 15, l4 = l >> 4;
  const int g = w >> 2;            // gate r,z,n
  const int u = (w >> 1) & 1;      // col half
  const int kh = w & 1;            // k half (512)

  __shared__ __align__(16) char smem[131072];
  __shared__ int role_sh;

  // self-organized placement: 1 WG/CU (128KB LDS) -> exactly 32 WGs per XCD
  unsigned xcc;
  asm volatile("s_getreg_b32 %0, hwreg(HW_REG_XCC_ID)" : "=s"(xcc));
  xcc &= 7u;
  if (tid == 0) {
    int rank = __hip_atomic_fetch_add(&xcdcnt[xcc], 1, __ATOMIC_RELAXED, __HIP_MEMORY_SCOPE_AGENT);
    int role = -1;
    if (xcc == 0 && rank < 32) role = rank;            // L0 worker on XCD0
    else if (xcc == 1 && rank < 32) role = 32 + rank;  // L1 worker on XCD1
    role_sh = role;
  }
  __syncthreads();
  const int role = role_sh;
  if (role < 0) return;   // 192 WGs exit

  const int layer = (role < 32) ? 0 : 1;
  const int c = (layer == 0) ? role : role - 32;
  const int n0c = c * 32;

  const unsigned short* wrowA = wihb + (size_t)layer * 3145728 +
      (size_t)(g * 1024 + n0c + u * 16 + l15) * 1024 + kh * 512 + l4 * 8;
  const unsigned short* wrowB = whhb + (size_t)layer * 3145728 +
      (size_t)(g * 1024 + n0c + u * 16 + l15) * 1024 + kh * 512 + l4 * 8;

  float bir[3][4], bhr[3][4];
  {
    int j0 = (tid & 7) << 2;
    #pragma unroll
    for (int q = 0; q < 4; ++q)
      #pragma unroll
      for (int gg = 0; gg < 3; ++gg) {
        bir[gg][q] = bih[layer * 3072 + gg * 1024 + n0c + j0 + q];
        bhr[gg][q] = bhh[layer * 3072 + gg * 1024 + n0c + j0 + q];
      }
  }
  float hcr[4] = {0.f, 0.f, 0.f, 0.f};   // fp32 zoneout carry
  int dead = 0;

  auto gather = [&](const char* src, int sc0) {
    #pragma unroll
    for (int i = 0; i < 11; ++i) {
      int idx = w + i * 12;
      if (idx < 128) {
        int row = idx >> 1, hh = idx & 1;
        const char* ga = src + row * 2048 + ((hh * 1024 + l * 16) ^ ((row & 7) << 4));
        if (sc0) GLL_SC0(ga, smem + idx * 1024); else GLL_PLAIN(ga, smem + idx * 1024);
      }
    }
  };
  auto gemm = [&](const unsigned short* wrow, floatx4* acc) {
    #pragma unroll
    for (int ks = 0; ks < 16; ++ks) {
      bhalf8 bb = *(const bhalf8*)(wrow + ks * 32);
      #pragma unroll
      for (int m = 0; m < 4; ++m) {
        int row = m * 16 + l15;
        bhalf8 a = *(const bhalf8*)(smem + row * 2048 +
                   ((kh * 1024 + ks * 64 + l4 * 16) ^ ((row & 7) << 4)));
        acc[m] = __builtin_amdgcn_mfma_f32_16x16x32_bf16(a, bb, acc[m], 0, 0, 0);
      }
    }
  };
  // Gs: 24 planes [64][17] f32 = 104448 B (12 input-side + 12 h-side)
  auto dumpGs = [&](floatx4* acc, int sideofs) {
    float* Gsf = (float*)smem;
    #pragma unroll
    for (int m = 0; m < 4; ++m)
      #pragma unroll
      for (int i = 0; i < 4; ++i)
        Gsf[(sideofs + w) * 1088 + (m * 16 + l4 * 4 + i) * 17 + l15] = acc[m][i];
  };

  if (layer == 0) {
    // ====== L0 on XCD0: h0(s) = GRU(x(s), h0(s-1)); recurrence fully XCD-local ======
    for (int s = 0; s < NSLOTS; ++s) {
      if (s <= 499) {
        gather((const char*)xb + (size_t)s * 131072, 0);   // x(s), plain, pre-poll
        if (w == 0 && !dead) {
          int it = 0;
          for (;;) {
            int ok = (l < 32) ? (cloadi(&flgL0rem[l]) >= s)        // peers done s-1
                              : (cloadi(&flgL1rem[l - 32]) >= s - 1); // h0rem[s&1] free
            if (__all(ok)) break;
            __builtin_amdgcn_s_sleep(2);
            if (++it > 300000) { dead = 1; break; }
          }
        }
        asm volatile("s_waitcnt vmcnt(0)" ::: "memory");
        __builtin_amdgcn_s_barrier();
        __builtin_amdgcn_sched_barrier(0);

        floatx4 accI[4], accH[4];
        #pragma unroll
        for (int m = 0; m < 4; ++m) {
          accI[m] = (floatx4){0.f, 0.f, 0.f, 0.f};
          accH[m] = (floatx4){0.f, 0.f, 0.f, 0.f};
        }
        gemm(wrowA, accI);                                  // x @ Wih0
        __syncthreads();
        // h0(s-1) from the XCD-local buffer: plain-stored by peers, sc0-gathered here
        gather(h0loc0 + (size_t)((s + 1) & 1) * 131072, 1);
        asm volatile("s_waitcnt vmcnt(0)" ::: "memory");
        __builtin_amdgcn_s_barrier();
        __builtin_amdgcn_sched_barrier(0);
        gemm(wrowB, accH);                                  // h0 @ Whh0
        __syncthreads();
        dumpGs(accI, 0);
        dumpGs(accH, 12);
        __syncthreads();
        float* Gsf = (float*)smem;
        if (tid < 512) {
          int b = tid >> 3, j0 = (tid & 7) << 2, u_ = j0 >> 4;
          char* houtL = h0loc0 + (size_t)(s & 1) * 131072;   // local (peers)
          char* houtR = h0rem  + (size_t)(s & 1) * 131072;   // agent (L1)
          union { unsigned long long ull; unsigned short us[4]; } pk;
          #pragma unroll
          for (int q = 0; q < 4; ++q) {
            int jj = (j0 + q) & 15;
            float gi[3], gh[3];
            #pragma unroll
            for (int gg = 0; gg < 3; ++gg) {
              int pw = gg * 4 + u_ * 2;
              gi[gg] = Gsf[pw * 1088 + b * 17 + jj] + Gsf[(pw + 1) * 1088 + b * 17 + jj];
              gh[gg] = Gsf[(12 + pw) * 1088 + b * 17 + jj] + Gsf[(12 + pw + 1) * 1088 + b * 17 + jj];
            }
            float ir = gi[0] + bir[0][q], iz = gi[1] + bir[1][q], inn = gi[2] + bir[2][q];
            float hr = gh[0] + bhr[0][q], hz = gh[1] + bhr[1][q], hn = gh[2] + bhr[2][q];
            float rg = 1.f / (1.f + expf(-(ir + hr)));
            float zg = 1.f / (1.f + expf(-(iz + hz)));
            float nc = tanhf(inn + rg * hn);
            float hp = hcr[q];
            float hnew = (1.f - zg) * nc + zg * hp;
            float hzo = 0.1f * hp + 0.9f * hnew;   // eval-mode zoneout
            hcr[q] = hzo;
            pk.us[q] = f2b(hzo);
          }
          size_t off = (size_t)b * 2048 + ((n0c + j0) << 1);
          *(volatile unsigned long long*)(houtL + off) = pk.ull;   // own L2 (peers)
          cstore8((unsigned long long*)(houtR + off), pk.ull);     // MALL (L1)
        }
      }
      __syncthreads();   // drains both stores before the flag
      if (tid == 0) cstorei(&flgL0rem[c], s + 1);
    }
  } else {
    // ====== L1 on XCD1: h1(s-1) = GRU(h0(s-1), h1(s-2)); y(s-2) ======
    for (int s = 0; s < NSLOTS; ++s) {
      if (s >= 1) {
        const bool doGemm = (s <= 500);
        if (w == 0 && !dead) {
          int it = 0;
          for (;;) {
            int ok = (l < 32) ? (cloadi(&flgL0rem[l]) >= s)        // h0(s-1) ready
                              : (cloadi(&flgL1rem[l - 32]) >= s);  // peers done s-1
            if (__all(ok)) break;
            __builtin_amdgcn_s_sleep(2);
            if (++it > 300000) { dead = 1; break; }
          }
        }
        __builtin_amdgcn_s_barrier();
        __builtin_amdgcn_sched_barrier(0);
        floatx4 accI[4], accH[4];
        #pragma unroll
        for (int m = 0; m < 4; ++m) {
          accI[m] = (floatx4){0.f, 0.f, 0.f, 0.f};
          accH[m] = (floatx4){0.f, 0.f, 0.f, 0.f};
        }
        if (doGemm) {
          // pull-copy h0(s-1): agent-load from h0rem (fresh at MALL), plain-store
          // into h0loc1 (own L2). Single writer XCD -> no staleness.
          if (w == 0 && !dead) {
            const char* src = h0rem + (size_t)((s + 1) & 1) * 131072;
            char* dst = h0loc1;
            int row = 2 * c + (l >> 5), off = (l & 31) * 64;
            #pragma unroll
            for (int k = 0; k < 8; ++k) {
              unsigned long long v = cload8((const unsigned long long*)(src + (size_t)row * 2048 + off + k * 8));
              *(volatile unsigned long long*)(dst + (size_t)row * 2048 + off + k * 8) = v;
            }
            asm volatile("s_waitcnt vmcnt(0)" ::: "memory");
            if (l == 0) cstorei(&flgCopy[c], s + 1);
            int it = 0;
            while (!__all(cloadi(&flgCopy[l & 31]) >= s + 1)) {
              __builtin_amdgcn_s_sleep(1);
              if (++it > 300000) { dead = 1; break; }
            }
          }
          __syncthreads();
          gather(h0loc1, 1);                                // h0(s-1) via own L2
          asm volatile("s_waitcnt vmcnt(0)" ::: "memory");
          __builtin_amdgcn_s_barrier();
          __builtin_amdgcn_sched_barrier(0);
          gemm(wrowA, accI);                                // h0 @ Wih1
          __syncthreads();
        }
        gather(h1loc + (size_t)(s & 1) * 131072, 1);        // h1(s-2) via own L2
        asm volatile("s_waitcnt vmcnt(0)" ::: "memory");
        __builtin_amdgcn_s_barrier();
        __builtin_amdgcn_sched_barrier(0);
        if (doGemm) gemm(wrowB, accH);                      // h1 @ Whh1
        // y(s-2) = h1(s-2) @ Wout^T + bout from the resident plane (Wout cvt on the fly)
        if (s >= 2 && c < 20 && w < 2) {
          int tile = c * 2 + w, bt = tile / 10, ct = tile % 10;
          int col = ct * 16 + l15;
          const float* wr = wout + (size_t)col * 1024 + l4 * 8;
          floatx4 accy = (floatx4){0.f, 0.f, 0.f, 0.f};
          #pragma unroll
          for (int ks = 0; ks < 32; ++ks) {
            union { bhalf8 v; unsigned short us[8]; } bw;
            #pragma unroll
            for (int e = 0; e < 8; ++e) bw.us[e] = f2b(wr[ks * 32 + e]);
            int row = bt * 16 + l15;
            bhalf8 a = *(const bhalf8*)(smem + row * 2048 +
                       ((ks * 64 + l4 * 16) ^ ((row & 7) << 4)));
            accy = __builtin_amdgcn_mfma_f32_16x16x32_bf16(a, bw.v, accy, 0, 0, 0);
          }
          float bo = bout[col];
          int t2 = s - 2;
          #pragma unroll
          for (int i = 0; i < 4; ++i) {
            int b = bt * 16 + l4 * 4 + i;
            out[(size_t)b * 80000 + (size_t)(col >> 1) * 1000 + t2 * 2 + (col & 1)] = accy[i] + bo;
          }
        }
        if (doGemm) {
          __syncthreads();
          dumpGs(accI, 0);
          dumpGs(accH, 12);
          __syncthreads();
          float* Gsf = (float*)smem;
          if (tid < 512) {
            int b = tid >> 3, j0 = (tid & 7) << 2, u_ = j0 >> 4;
            char* hout = h1loc + (size_t)((s + 1) & 1) * 131072;   // local only
            union { unsigned long long ull; unsigned short us[4]; } pk;
            #pragma unroll
            for (int q = 0; q < 4; ++q) {
              int jj = (j0 + q) & 15;
              float gi[3], gh[3];
              #pragma unroll
              for (int gg = 0; gg < 3; ++gg) {
                int pw = gg * 4 + u_ * 2;
                gi[gg] = Gsf[pw * 1088 + b * 17 + jj] + Gsf[(pw + 1) * 1088 + b * 17 + jj];
                gh[gg] = Gsf[(12 + pw) * 1088 + b * 17 + jj] + Gsf[(12 + pw + 1) * 1088 + b * 17 + jj];
              }
              float ir = gi[0] + bir[0][q], iz = gi[1] + bir[1][q], inn = gi[2] + bir[2][q];
              float hr = gh[0] + bhr[0][q], hz = gh[1] + bhr[1][q], hn = gh[2] + bhr[2][q];
              float rg = 1.f / (1.f + expf(-(ir + hr)));
              float zg = 1.f / (1.f + expf(-(iz + hz)));
              float nc = tanhf(inn + rg * hn);
              float hp = hcr[q];
              float hnew = (1.f - zg) * nc + zg * hp;
              float hzo = 0.1f * hp + 0.9f * hnew;
              hcr[q] = hzo;
              pk.us[q] = f2b(hzo);
            }
            *(volatile unsigned long long*)(hout + (size_t)b * 2048 + ((n0c + j0) << 1)) = pk.ull;
          }
        }
      }
      __syncthreads();
      if (tid == 0) cstorei(&flgL1rem[c], s + 1);
    }
  }
}

extern "C" void kernel_launch(void* const* d_in, const int* in_sizes, int n_in,
                              void* d_out, int out_size, void* d_ws, size_t ws_size,
                              hipStream_t stream) {
  const float* res  = (const float*)d_in[0];
  const float* Wih  = (const float*)d_in[1];
  const float* Whh  = (const float*)d_in[2];
  const float* bih  = (const float*)d_in[3];
  const float* bhh  = (const float*)d_in[4];
  const float* Wout = (const float*)d_in[5];
  const float* bout = (const float*)d_in[6];
  float* out = (float*)d_out;
  char* ws = (char*)d_ws;
  if (ws_size < 91620352u) return;

  unsigned short* wihb = (unsigned short*)(ws + 918528);
  unsigned short* whhb = (unsigned short*)(ws + 13501440);
  unsigned short* xb   = (unsigned short*)(ws + 26084352);

  hipMemsetAsync(ws, 0, 918528, stream);
  prep_w<<<4096, 256, 0, stream>>>(Wih, Whh, wihb, whhb);
  prep_x<<<dim3(16, 32, 64), dim3(32, 8), 0, stream>>>(res, xb);
  gru_main<<<256, BLOCK, 0, stream>>>(xb, wihb, whhb, Wout, bih, bhh, bout, ws, out);
}

// Round 13
// 21753.552 us; speedup vs baseline: 1.0721x; 1.0721x over previous
//
#include <hip/hip_runtime.h>

typedef __attribute__((ext_vector_type(8))) short bhalf8;
typedef __attribute__((ext_vector_type(4))) float floatx4;

#define NSLOTS 502
#define BLOCK 768   // 12 waves = gate(3) x colhalf(2) x khalf(2)

#define AS1 __attribute__((address_space(1)))
#define AS3 __attribute__((address_space(3)))
// aux=17: sc0|sc1 agent-coherent (MALL).  aux=1: sc0 own-L2.  aux=0: plain cached.
#define GLL_COH(g, s)   __builtin_amdgcn_global_load_lds((const AS1 unsigned*)(g), (AS3 unsigned*)(s), 16, 0, 17)
#define GLL_SC0(g, s)   __builtin_amdgcn_global_load_lds((const AS1 unsigned*)(g), (AS3 unsigned*)(s), 16, 0, 1)
#define GLL_PLAIN(g, s) __builtin_amdgcn_global_load_lds((const AS1 unsigned*)(g), (AS3 unsigned*)(s), 16, 0, 0)

__device__ __forceinline__ unsigned short f2b(float f) {
  unsigned u = __float_as_uint(f);
  return (unsigned short)((u + 0x7FFFu + ((u >> 16) & 1u)) >> 16);
}
// agent-scope (sc0|sc1) — ALL sync flags use these, both sides (proven R3/R4/R8/R11).
__device__ __forceinline__ int cloadi(const int* p) {
  return __hip_atomic_load(p, __ATOMIC_RELAXED, __HIP_MEMORY_SCOPE_AGENT);
}
__device__ __forceinline__ void cstorei(int* p, int v) {
  __hip_atomic_store(p, v, __ATOMIC_RELAXED, __HIP_MEMORY_SCOPE_AGENT);
}
__device__ __forceinline__ void cstore8(unsigned long long* p, unsigned long long v) {
  __hip_atomic_store(p, v, __ATOMIC_RELAXED, __HIP_MEMORY_SCOPE_AGENT);
}

__global__ void prep_w(const float* __restrict__ wih, const float* __restrict__ whh,
                       unsigned short* __restrict__ wihb, unsigned short* __restrict__ whhb) {
  size_t i0 = (size_t)blockIdx.x * blockDim.x + threadIdx.x;
  size_t stride = (size_t)gridDim.x * blockDim.x;
  for (size_t i = i0; i < 6291456u; i += stride) { wihb[i] = f2b(wih[i]); whhb[i] = f2b(whh[i]); }
}

// res_output (B=64, H=1024, T=500) f32 -> xb (T, B, H) bf16 (coalesced transpose)
__global__ void prep_x(const float* __restrict__ x, unsigned short* __restrict__ xb) {
  __shared__ float tile[32][33];
  int b = blockIdx.z;
  int h0 = blockIdx.y * 32, t0 = blockIdx.x * 32;
  int tx = threadIdx.x, ty = threadIdx.y;
  #pragma unroll
  for (int i = 0; i < 32; i += 8) {
    int t = t0 + tx;
    if (t < 500) tile[ty + i][tx] = x[((size_t)b * 1024 + h0 + ty + i) * 500 + t];
  }
  __syncthreads();
  #pragma unroll
  for (int i = 0; i < 32; i += 8) {
    int t = t0 + ty + i;
    if (t < 500) xb[((size_t)t * 64 + b) * 1024 + h0 + tx] = f2b(tile[tx][ty + i]);
  }
}

// ws layout (bytes). Discipline: flags & h0rem = agent both sides [A];
// h0loc0/h1loc = plain-store + sc0-load within one XCD only [L:x] (R11-proven).
// 0    flgL0rem[32] [A]   128  flgL1rem[32] [A]   512 xcdcnt[8] [A]
// 1024    h0rem[3] x131072 [A]    (L0 -> L1 handoff, ring 3)   -> 394240
// 394240  h0loc0[2] x131072 [L:0] (L0 recurrence, XCD0-local)  -> 656384
// 656384  h1loc[2]  x131072 [L:1] (L1 recurrence, XCD1-local)  -> 918528
// --- zero region ends 918528 ---
// 918528   Wihb 12582912 -> 13501440
// 13501440 Whhb 12582912 -> 26084352
// 26084352 Xb (500*64*1024 bf16) -> 91620352

__launch_bounds__(BLOCK, 1)
__global__ void gru_main(const unsigned short* __restrict__ xb,
                         const unsigned short* __restrict__ wihb,
                         const unsigned short* __restrict__ whhb,
                         const float* __restrict__ wout,
                         const float* __restrict__ bih, const float* __restrict__ bhh,
                         const float* __restrict__ bout,
                         char* __restrict__ wsb, float* __restrict__ out) {
  int* flgL0rem = (int*)wsb;
  int* flgL1rem = (int*)(wsb + 128);
  int* xcdcnt   = (int*)(wsb + 512);
  char* h0rem  = wsb + 1024;
  char* h0loc0 = wsb + 394240;
  char* h1loc  = wsb + 656384;

  const int tid = threadIdx.x;
  const int w = tid >> 6;
  const int l = tid & 63;
  const int l15 = l & 15, l4 = l >> 4;
  const int g = w >> 2;            // gate r,z,n
  const int u = (w >> 1) & 1;      // col half (16 cols)
  const int kh = w & 1;            // k half (512)

  __shared__ __align__(16) char smem[131072];
  __shared__ int role_sh;

  // self-organized placement: 1 WG/CU (128KB LDS) -> exactly 32 WGs per XCD
  unsigned xcc;
  asm volatile("s_getreg_b32 %0, hwreg(HW_REG_XCC_ID)" : "=s"(xcc));
  xcc &= 7u;
  if (tid == 0) {
    int rank = __hip_atomic_fetch_add(&xcdcnt[xcc], 1, __ATOMIC_RELAXED, __HIP_MEMORY_SCOPE_AGENT);
    int role = -1;
    if (xcc == 0 && rank < 32) role = rank;            // L0 worker on XCD0
    else if (xcc == 1 && rank < 32) role = 32 + rank;  // L1 worker on XCD1
    role_sh = role;
  }
  __syncthreads();
  const int role = role_sh;
  if (role < 0) return;

  const int layer = (role < 32) ? 0 : 1;
  const int c = (layer == 0) ? role : role - 32;
  const int n0c = c * 32;

  const unsigned short* wrowA = wihb + (size_t)layer * 3145728 +
      (size_t)(g * 1024 + n0c + u * 16 + l15) * 1024 + kh * 512 + l4 * 8;
  const unsigned short* wrowB = whhb + (size_t)layer * 3145728 +
      (size_t)(g * 1024 + n0c + u * 16 + l15) * 1024 + kh * 512 + l4 * 8;

  // Whh slice VGPR-resident: 16 x bhalf8 = 64 VGPR/lane. No per-slot anchor (R5 lesson);
  // if remat'd, degrades to L2 streaming (correct, R11 parity).
  bhalf8 wregB[16];
  #pragma unroll
  for (int i = 0; i < 16; ++i) wregB[i] = *(const bhalf8*)(wrowB + i * 32);

  float bir[3][4], bhr[3][4];
  {
    int j0 = (tid & 7) << 2;
    #pragma unroll
    for (int q = 0; q < 4; ++q)
      #pragma unroll
      for (int gg = 0; gg < 3; ++gg) {
        bir[gg][q] = bih[layer * 3072 + gg * 1024 + n0c + j0 + q];
        bhr[gg][q] = bhh[layer * 3072 + gg * 1024 + n0c + j0 + q];
      }
  }
  float hcr[4] = {0.f, 0.f, 0.f, 0.f};   // fp32 zoneout carry
  int dead = 0;

  auto gather = [&](const char* src, int mode) {   // 0=plain, 1=sc0(own L2), 2=agent(MALL)
    #pragma unroll
    for (int i = 0; i < 11; ++i) {
      int idx = w + i * 12;
      if (idx < 128) {
        int row = idx >> 1, hh = idx & 1;
        const char* ga = src + row * 2048 + ((hh * 1024 + l * 16) ^ ((row & 7) << 4));
        if (mode == 2) GLL_COH(ga, smem + idx * 1024);
        else if (mode == 1) GLL_SC0(ga, smem + idx * 1024);
        else GLL_PLAIN(ga, smem + idx * 1024);
      }
    }
  };
  // streamed gemm: weights via non-temporal loads (don't evict h/flag lines from L2)
  auto gemmS = [&](const unsigned short* wrow, floatx4* acc) {
    #pragma unroll
    for (int ks = 0; ks < 16; ++ks) {
      bhalf8 bb = __builtin_nontemporal_load((const bhalf8*)(wrow + ks * 32));
      #pragma unroll
      for (int m = 0; m < 4; ++m) {
        int row = m * 16 + l15;
        bhalf8 a = *(const bhalf8*)(smem + row * 2048 +
                   ((kh * 1024 + ks * 64 + l4 * 16) ^ ((row & 7) << 4)));
        acc[m] = __builtin_amdgcn_mfma_f32_16x16x32_bf16(a, bb, acc[m], 0, 0, 0);
      }
    }
  };
  // register gemm: zero weight memory traffic
  auto gemmR = [&](floatx4* acc) {
    #pragma unroll
    for (int ks = 0; ks < 16; ++ks)
      #pragma unroll
      for (int m = 0; m < 4; ++m) {
        int row = m * 16 + l15;
        bhalf8 a = *(const bhalf8*)(smem + row * 2048 +
                   ((kh * 1024 + ks * 64 + l4 * 16) ^ ((row & 7) << 4)));
        acc[m] = __builtin_amdgcn_mfma_f32_16x16x32_bf16(a, wregB[ks], acc[m], 0, 0, 0);
      }
  };
  // Gs: 24 planes [64][17] f32 = 104448 B
  auto dumpGs = [&](floatx4* acc, int sideofs) {
    float* Gsf = (float*)smem;
    #pragma unroll
    for (int m = 0; m < 4; ++m)
      #pragma unroll
      for (int i = 0; i < 4; ++i)
        Gsf[(sideofs + w) * 1088 + (m * 16 + l4 * 4 + i) * 17 + l15] = acc[m][i];
  };
  auto epilogue = [&](char* houtL, char* houtR) {   // houtR may be null
    float* Gsf = (float*)smem;
    if (tid < 512) {
      int b = tid >> 3, j0 = (tid & 7) << 2, u_ = j0 >> 4;
      union { unsigned long long ull; unsigned short us[4]; } pk;
      #pragma unroll
      for (int q = 0; q < 4; ++q) {
        int jj = (j0 + q) & 15;
        float gi[3], gh[3];
        #pragma unroll
        for (int gg = 0; gg < 3; ++gg) {
          int pw = gg * 4 + u_ * 2;
          gi[gg] = Gsf[pw * 1088 + b * 17 + jj] + Gsf[(pw + 1) * 1088 + b * 17 + jj];
          gh[gg] = Gsf[(12 + pw) * 1088 + b * 17 + jj] + Gsf[(12 + pw + 1) * 1088 + b * 17 + jj];
        }
        float ir = gi[0] + bir[0][q], iz = gi[1] + bir[1][q], inn = gi[2] + bir[2][q];
        float hr = gh[0] + bhr[0][q], hz = gh[1] + bhr[1][q], hn = gh[2] + bhr[2][q];
        float rg = 1.f / (1.f + expf(-(ir + hr)));
        float zg = 1.f / (1.f + expf(-(iz + hz)));
        float nc = tanhf(inn + rg * hn);
        float hp = hcr[q];
        float hnew = (1.f - zg) * nc + zg * hp;
        float hzo = 0.1f * hp + 0.9f * hnew;   // eval-mode zoneout
        hcr[q] = hzo;
        pk.us[q] = f2b(hzo);
      }
      size_t off = (size_t)b * 2048 + ((n0c + j0) << 1);
      *(volatile unsigned long long*)(houtL + off) = pk.ull;           // local (own L2)
      if (houtR) cstore8((unsigned long long*)(houtR + off), pk.ull);  // agent (MALL)
    }
  };

  if (layer == 0) {
    // ====== L0 on XCD0: h0(s) = GRU(x(s), h0(s-1)) ======
    for (int s = 0; s < NSLOTS; ++s) {
      if (s <= 499) {
        gather((const char*)xb + (size_t)s * 131072, 0);   // x(s), plain, pre-poll
        if (w == 0 && !dead) {
          int it = 0;
          for (;;) {
            int ok = (l < 32) ? (cloadi(&flgL0rem[l]) >= s)            // peers done s-1
                              : (cloadi(&flgL1rem[l - 32]) >= s - 1);  // h0rem[s%3] free
            if (__all(ok)) break;
            __builtin_amdgcn_s_sleep(2);
            if (++it > 300000) { dead = 1; break; }
          }
        }
        asm volatile("s_waitcnt vmcnt(0)" ::: "memory");
        __builtin_amdgcn_s_barrier();
        __builtin_amdgcn_sched_barrier(0);

        floatx4 accI[4], accH[4];
        #pragma unroll
        for (int m = 0; m < 4; ++m) {
          accI[m] = (floatx4){0.f, 0.f, 0.f, 0.f};
          accH[m] = (floatx4){0.f, 0.f, 0.f, 0.f};
        }
        gemmS(wrowA, accI);                                   // x @ Wih0 (nt stream)
        __syncthreads();
        gather(h0loc0 + (size_t)((s + 1) & 1) * 131072, 1);   // h0(s-1), own-L2
        asm volatile("s_waitcnt vmcnt(0)" ::: "memory");
        __builtin_amdgcn_s_barrier();
        __builtin_amdgcn_sched_barrier(0);
        gemmR(accH);                                          // h0 @ Whh0 (VGPR weights)
        __syncthreads();
        dumpGs(accI, 0);
        dumpGs(accH, 12);
        __syncthreads();
        epilogue(h0loc0 + (size_t)(s & 1) * 131072,           // peers (local)
                 h0rem + (size_t)(s % 3) * 131072);           // L1 (agent)
      }
      __syncthreads();   // drain stores before flag
      if (tid == 0) cstorei(&flgL0rem[c], s + 1);
    }
  } else {
    // ====== L1 on XCD1: h1(s-1) = GRU(h0(s-1), h1(s-2)); y(s-2) ======
    for (int s = 0; s < NSLOTS; ++s) {
      if (s >= 1) {
        const bool doGemm = (s <= 500);
        if (w == 0 && !dead) {
          int need0 = doGemm ? s : 0;
          int it = 0;
          for (;;) {
            int ok = (l < 32) ? (cloadi(&flgL0rem[l]) >= need0)        // h0(s-1) ready
                              : (cloadi(&flgL1rem[l - 32]) >= s);      // peers done s-1
            if (__all(ok)) break;
            __builtin_amdgcn_s_sleep(2);
            if (++it > 300000) { dead = 1; break; }
          }
        }
        __builtin_amdgcn_s_barrier();
        __builtin_amdgcn_sched_barrier(0);
        floatx4 accI[4], accH[4];
        #pragma unroll
        for (int m = 0; m < 4; ++m) {
          accI[m] = (floatx4){0.f, 0.f, 0.f, 0.f};
          accH[m] = (floatx4){0.f, 0.f, 0.f, 0.f};
        }
        if (doGemm) {
          gather(h0rem + (size_t)((s - 1) % 3) * 131072, 2);  // h0(s-1), agent burst
          asm volatile("s_waitcnt vmcnt(0)" ::: "memory");
          __builtin_amdgcn_s_barrier();
          __builtin_amdgcn_sched_barrier(0);
          gemmS(wrowA, accI);                                 // h0 @ Wih1 (nt stream)
          __syncthreads();
        }
        gather(h1loc + (size_t)(s & 1) * 131072, 1);          // h1(s-2), own-L2
        asm volatile("s_waitcnt vmcnt(0)" ::: "memory");
        __builtin_amdgcn_s_barrier();
        __builtin_amdgcn_sched_barrier(0);
        if (doGemm) gemmR(accH);                              // h1 @ Whh1 (VGPR weights)
        // y(s-2) = h1(s-2) @ Wout^T + bout from the resident LDS plane
        if (s >= 2 && c < 20 && w < 2) {
          int tile = c * 2 + w, bt = tile / 10, ct = tile % 10;
          int col = ct * 16 + l15;
          const float* wr = wout + (size_t)col * 1024 + l4 * 8;
          floatx4 accy = (floatx4){0.f, 0.f, 0.f, 0.f};
          #pragma unroll
          for (int ks = 0; ks < 32; ++ks) {
            union { bhalf8 v; unsigned short us[8]; } bw;
            #pragma unroll
            for (int e = 0; e < 8; ++e) bw.us[e] = f2b(wr[ks * 32 + e]);
            int row = bt * 16 + l15;
            bhalf8 a = *(const bhalf8*)(smem + row * 2048 +
                       ((ks * 64 + l4 * 16) ^ ((row & 7) << 4)));
            accy = __builtin_amdgcn_mfma_f32_16x16x32_bf16(a, bw.v, accy, 0, 0, 0);
          }
          float bo = bout[col];
          int t2 = s - 2;
          #pragma unroll
          for (int i = 0; i < 4; ++i) {
            int b = bt * 16 + l4 * 4 + i;
            out[(size_t)b * 80000 + (size_t)(col >> 1) * 1000 + t2 * 2 + (col & 1)] = accy[i] + bo;
          }
        }
        if (doGemm) {
          __syncthreads();
          dumpGs(accI, 0);
          dumpGs(accH, 12);
          __syncthreads();
          epilogue(h1loc + (size_t)((s + 1) & 1) * 131072, nullptr);  // local only
        }
      }
      __syncthreads();
      if (tid == 0) cstorei(&flgL1rem[c], s + 1);
    }
  }
}

extern "C" void kernel_launch(void* const* d_in, const int* in_sizes, int n_in,
                              void* d_out, int out_size, void* d_ws, size_t ws_size,
                              hipStream_t stream) {
  const float* res  = (const float*)d_in[0];
  const float* Wih  = (const float*)d_in[1];
  const float* Whh  = (const float*)d_in[2];
  const float* bih  = (const float*)d_in[3];
  const float* bhh  = (const float*)d_in[4];
  const float* Wout = (const float*)d_in[5];
  const float* bout = (const float*)d_in[6];
  float* out = (float*)d_out;
  char* ws = (char*)d_ws;
  if (ws_size < 91620352u) return;

  unsigned short* wihb = (unsigned short*)(ws + 918528);
  unsigned short* whhb = (unsigned short*)(ws + 13501440);
  unsigned short* xb   = (unsigned short*)(ws + 26084352);

  hipMemsetAsync(ws, 0, 918528, stream);
  prep_w<<<4096, 256, 0, stream>>>(Wih, Whh, wihb, whhb);
  prep_x<<<dim3(16, 32, 64), dim3(32, 8), 0, stream>>>(res, xb);
  gru_main<<<256, BLOCK, 0, stream>>>(xb, wihb, whhb, Wout, bih, bhh, bout, ws, out);
}

// Round 14
// 17748.097 us; speedup vs baseline: 1.3141x; 1.2257x over previous
//
#include <hip/hip_runtime.h>

typedef __attribute__((ext_vector_type(8))) short bhalf8;
typedef __attribute__((ext_vector_type(4))) float floatx4;

#define NSLOTS 502
#define NWG 64
#define BLOCK 1024   // 16 waves: 12 compute (side2 x gate3 x colhalf2) + 4 stagers

#define AS1 __attribute__((address_space(1)))
#define AS3 __attribute__((address_space(3)))
// aux=17: sc0|sc1 agent-coherent (cross-XCD fresh). aux=0: plain cached.
#define GLL_COH(g, s)   __builtin_amdgcn_global_load_lds((const AS1 unsigned*)(g), (AS3 unsigned*)(s), 16, 0, 17)
#define GLL_PLAIN(g, s) __builtin_amdgcn_global_load_lds((const AS1 unsigned*)(g), (AS3 unsigned*)(s), 16, 0, 0)

__device__ __forceinline__ unsigned short f2b(float f) {
  unsigned u = __float_as_uint(f);
  return (unsigned short)((u + 0x7FFFu + ((u >> 16) & 1u)) >> 16);
}
// agent-scope (sc0|sc1): flags and cross-XCD h rings, BOTH sides (proven R3/R4/R8/R11/R13)
__device__ __forceinline__ int cloadi(const int* p) {
  return __hip_atomic_load(p, __ATOMIC_RELAXED, __HIP_MEMORY_SCOPE_AGENT);
}
__device__ __forceinline__ void cstorei(int* p, int v) {
  __hip_atomic_store(p, v, __ATOMIC_RELAXED, __HIP_MEMORY_SCOPE_AGENT);
}
__device__ __forceinline__ unsigned long long cload8(const unsigned long long* p) {
  return __hip_atomic_load(p, __ATOMIC_RELAXED, __HIP_MEMORY_SCOPE_AGENT);
}
__device__ __forceinline__ void cstore8(unsigned long long* p, unsigned long long v) {
  __hip_atomic_store(p, v, __ATOMIC_RELAXED, __HIP_MEMORY_SCOPE_AGENT);
}

__global__ void prep_w(const float* __restrict__ wih, const float* __restrict__ whh,
                       unsigned short* __restrict__ wihb, unsigned short* __restrict__ whhb) {
  size_t i0 = (size_t)blockIdx.x * blockDim.x + threadIdx.x;
  size_t stride = (size_t)gridDim.x * blockDim.x;
  for (size_t i = i0; i < 6291456u; i += stride) { wihb[i] = f2b(wih[i]); whhb[i] = f2b(whh[i]); }
}

// res_output (B=64, H=1024, T=500) f32 -> xb (T, B, H) bf16 (coalesced transpose)
__global__ void prep_x(const float* __restrict__ x, unsigned short* __restrict__ xb) {
  __shared__ float tile[32][33];
  int b = blockIdx.z;
  int h0 = blockIdx.y * 32, t0 = blockIdx.x * 32;
  int tx = threadIdx.x, ty = threadIdx.y;
  #pragma unroll
  for (int i = 0; i < 32; i += 8) {
    int t = t0 + tx;
    if (t < 500) tile[ty + i][tx] = x[((size_t)b * 1024 + h0 + ty + i) * 500 + t];
  }
  __syncthreads();
  #pragma unroll
  for (int i = 0; i < 32; i += 8) {
    int t = t0 + ty + i;
    if (t < 500) xb[((size_t)t * 64 + b) * 1024 + h0 + tx] = f2b(tile[tx][ty + i]);
  }
}

// ws layout (bytes). All cross-WG buffers AGENT-scope both sides.
// 0      f0[32] (L0 flags)   128  f1[32] (L1 flags)   pad to 1024
// 1024   h0b[3] x 131072  (bf16 64x1024, ring 3)  -> 394240
// 394240 h1b[2] x 131072  (ring 2)                -> 656384
// --- zero region ends 656384 ---
// 656384   Wihb 12582912 -> 13239296
// 13239296 Whhb 12582912 -> 25822208
// 25822208 Xb (500*64*1024 bf16) -> 91358208

__launch_bounds__(BLOCK, 1)
__global__ void gru_main(const unsigned short* __restrict__ xb,
                         const unsigned short* __restrict__ wihb,
                         const unsigned short* __restrict__ whhb,
                         const float* __restrict__ wout,
                         const float* __restrict__ bih, const float* __restrict__ bhh,
                         const float* __restrict__ bout,
                         char* __restrict__ wsb, float* __restrict__ out) {
  int* f0 = (int*)wsb;
  int* f1 = (int*)(wsb + 128);
  char* h0b = wsb + 1024;       // ring 3 x 131072
  char* h1b = wsb + 394240;     // ring 2 x 131072

  const int wg = blockIdx.x;
  const int layer = wg >> 5;    // 0: h0(s); 1: h1(s-1)
  const int c = wg & 31;        // 32 output cols: n0c..n0c+32
  const int n0c = c * 32;
  const int tid = threadIdx.x;
  const int w = tid >> 6;       // 0..15
  const int l = tid & 63;
  const int l15 = l & 15, l4 = l >> 4;
  // compute-wave roles (w<12): side, gate, col-half
  const int sd = w / 6;
  const int g = (w % 6) >> 1;
  const int u = w & 1;

  // LDS: 4-slot ring x 32KB chunk ([side 16KB][row64 x 256B], src-pre-swizzled).
  // Gs overlay (12 planes [64][17] f32 = 52224B) after the k-loop.
  __shared__ __align__(16) char smem[131072];

  const unsigned short* wrow = ((sd == 0) ? wihb : whhb) + (size_t)layer * 3145728 +
      (size_t)(g * 1024 + n0c + u * 16 + l15) * 1024 + l4 * 8;

  float bir[3][4], bhr[3][4];
  {
    int j0 = (tid & 7) << 2;
    #pragma unroll
    for (int q = 0; q < 4; ++q)
      #pragma unroll
      for (int gg = 0; gg < 3; ++gg) {
        bir[gg][q] = bih[layer * 3072 + gg * 1024 + n0c + j0 + q];
        bhr[gg][q] = bhh[layer * 3072 + gg * 1024 + n0c + j0 + q];
      }
  }
  float hcr[4] = {0.f, 0.f, 0.f, 0.f};   // fp32 zoneout carry
  int dead = 0;

  for (int s = 0; s < NSLOTS; ++s) {
    const bool act = (layer == 0) ? (s <= 499) : (s >= 1);
    const bool doGemm = (layer == 0) ? (s <= 499) : (s >= 1 && s <= 500);

    if (act) {
      // ---- poll (w0, lane-parallel, agent, bounded)
      if (w == 0 && !dead) {
        int it = 0;
        for (;;) {
          int ok;
          if (layer == 0)
            ok = (l < 32) ? (cloadi(&f0[l]) >= s) : (cloadi(&f1[l - 32]) >= s - 1);
          else
            ok = (l < 32) ? (cloadi(&f0[l]) >= s) : (cloadi(&f1[l - 32]) >= s);
          if (__all(ok)) break;
          __builtin_amdgcn_s_sleep(2);
          if (++it > 300000) { dead = 1; break; }
        }
      }
      __builtin_amdgcn_s_barrier();
      __builtin_amdgcn_sched_barrier(0);

      const char* src0;  // side 0
      const char* src1;  // side 1
      if (layer == 0) {
        src0 = (const char*)xb + (size_t)s * 131072;       // x(s): plain
        src1 = h0b + (size_t)((s + 2) % 3) * 131072;       // h0(s-1): agent
      } else {
        src0 = h0b + (size_t)((s - 1) % 3) * 131072;       // h0(s-1): agent
        src1 = h1b + (size_t)(s & 1) * 131072;             // h1(s-2): agent
      }

      // stager waves (w>=12): pure global_load_lds -> clean vmcnt counting
      auto issue_chunk = [&](int kc) {
        char* slot = smem + ((kc & 3) << 15);
        #pragma unroll
        for (int i = 0; i < 8; ++i) {
          int idx = (w - 12) * 8 + i;             // 0..31
          int side = idx >> 4, sub = idx & 15;    // 16 instrs per side
          int row = sub * 4 + (l >> 4);           // 4 rows per instr
          int kb = (l & 15) * 16;                 // 0..255 within the chunk slice
          const char* ga = (side ? src1 : src0) + row * 2048 + kc * 256 +
                           (kb ^ ((row & 7) << 4));   // pre-swizzled source
          char* la = slot + side * 16384 + sub * 1024;
          if (side == 0 && layer == 0) GLL_PLAIN(ga, la); else GLL_COH(ga, la);
        }
      };

      floatx4 acc[4];
      #pragma unroll
      for (int m = 0; m < 4; ++m) acc[m] = (floatx4){0.f, 0.f, 0.f, 0.f};

      if (doGemm) {
        if (w >= 12) {
          issue_chunk(0); issue_chunk(1); issue_chunk(2);
          asm volatile("s_waitcnt vmcnt(16)" ::: "memory");   // chunk 0 landed
        }
        __builtin_amdgcn_s_barrier();
        __builtin_amdgcn_sched_barrier(0);

        #pragma unroll
        for (int kc = 0; kc < 8; ++kc) {
          if (w < 12) {
            const char* Ab = smem + ((kc & 3) << 15) + sd * 16384;
            #pragma unroll
            for (int klL = 0; klL < 4; ++klL) {
              bhalf8 bb = *(const bhalf8*)(wrow + (kc * 4 + klL) * 32);  // L2-resident
              #pragma unroll
              for (int m = 0; m < 4; ++m) {
                int row = m * 16 + l15;
                bhalf8 a = *(const bhalf8*)(Ab + row * 256 +
                           ((klL * 64 + l4 * 16) ^ ((row & 7) << 4)));
                acc[m] = __builtin_amdgcn_mfma_f32_16x16x32_bf16(a, bb, acc[m], 0, 0, 0);
              }
            }
          } else {
            if (kc < 5) issue_chunk(kc + 3);
            if (kc < 5)      asm volatile("s_waitcnt vmcnt(16)" ::: "memory");
            else if (kc == 5) asm volatile("s_waitcnt vmcnt(8)" ::: "memory");
            else if (kc == 6) asm volatile("s_waitcnt vmcnt(0)" ::: "memory");
          }
          __builtin_amdgcn_s_barrier();
          __builtin_amdgcn_sched_barrier(0);
        }
        __syncthreads();   // ring reads done -> safe to overlay Gs

        // Gs: plane per compute wave: [64][17] f32, idx = w (sd*6 + g*2 + u)
        float* Gsf = (float*)smem;
        if (w < 12) {
          #pragma unroll
          for (int m = 0; m < 4; ++m)
            #pragma unroll
            for (int i = 0; i < 4; ++i)
              Gsf[w * 1088 + (m * 16 + l4 * 4 + i) * 17 + l15] = acc[m][i];
        }
        __syncthreads();

        // epilogue (tid<512 = compute waves): b = tid>>3, j0 = (tid&7)*4
        if (tid < 512) {
          int b = tid >> 3, j0 = (tid & 7) << 2;
          char* hout = (layer == 0) ? h0b + (size_t)(s % 3) * 131072
                                    : h1b + (size_t)((s + 1) & 1) * 131072;
          union { unsigned long long ull; unsigned short us[4]; } pk;
          #pragma unroll
          for (int q = 0; q < 4; ++q) {
            int j = j0 + q, u_ = j >> 4, jj = j & 15;
            float gi[3], gh[3];
            #pragma unroll
            for (int gg = 0; gg < 3; ++gg) {
              gi[gg] = Gsf[(0 * 6 + gg * 2 + u_) * 1088 + b * 17 + jj];
              gh[gg] = Gsf[(1 * 6 + gg * 2 + u_) * 1088 + b * 17 + jj];
            }
            float ir = gi[0] + bir[0][q], iz = gi[1] + bir[1][q], inn = gi[2] + bir[2][q];
            float hr = gh[0] + bhr[0][q], hz = gh[1] + bhr[1][q], hn = gh[2] + bhr[2][q];
            float rg = 1.f / (1.f + expf(-(ir + hr)));
            float zg = 1.f / (1.f + expf(-(iz + hz)));
            float nc = tanhf(inn + rg * hn);
            float hp = hcr[q];
            float hnew = (1.f - zg) * nc + zg * hp;
            float hzo = 0.1f * hp + 0.9f * hnew;   // eval-mode zoneout
            hcr[q] = hzo;
            pk.us[q] = f2b(hzo);
          }
          cstore8((unsigned long long*)(hout + (size_t)b * 2048 + ((n0c + j0) << 1)), pk.ull);
        }
      }

      // y(s-2) by L1 STAGERS (idle post-loop): h1(s-2) flagged (poll f1>=s), agent reads.
      if (layer == 1 && c < 10 && w >= 12 && s >= 2) {
        const char* Ay = h1b + (size_t)(s & 1) * 131072;    // h1(s-2)
        int bt = w - 12;                                    // 4 row-tiles
        const unsigned long long* arow =
            (const unsigned long long*)(Ay + (size_t)(bt * 16 + l15) * 2048);
        int col = c * 16 + l15;
        const float* wr = wout + (size_t)col * 1024 + l4 * 8;
        floatx4 accy = (floatx4){0.f, 0.f, 0.f, 0.f};
        #pragma unroll
        for (int ks = 0; ks < 32; ++ks) {
          int kg = ks * 32 + l4 * 8;
          union { unsigned long long uu[2]; bhalf8 v; } av;
          av.uu[0] = cload8(arow + (kg >> 2));
          av.uu[1] = cload8(arow + (kg >> 2) + 1);
          union { bhalf8 v; unsigned short us[8]; } bw;
          #pragma unroll
          for (int e = 0; e < 8; ++e) bw.us[e] = f2b(wr[ks * 32 + e]);
          accy = __builtin_amdgcn_mfma_f32_16x16x32_bf16(av.v, bw.v, accy, 0, 0, 0);
        }
        float bo = bout[col];
        int t2 = s - 2;
        #pragma unroll
        for (int i = 0; i < 4; ++i) {
          int b = bt * 16 + l4 * 4 + i;
          out[(size_t)b * 80000 + (size_t)(col >> 1) * 1000 + t2 * 2 + (col & 1)] = accy[i] + bo;
        }
      }
    }

    __syncthreads();   // drain all stores (agent h + out) before flagging
    if (tid == 0) {
      if (layer == 0) cstorei(&f0[c], s + 1); else cstorei(&f1[c], s + 1);
    }
  }
}

extern "C" void kernel_launch(void* const* d_in, const int* in_sizes, int n_in,
                              void* d_out, int out_size, void* d_ws, size_t ws_size,
                              hipStream_t stream) {
  const float* res  = (const float*)d_in[0];
  const float* Wih  = (const float*)d_in[1];
  const float* Whh  = (const float*)d_in[2];
  const float* bih  = (const float*)d_in[3];
  const float* bhh  = (const float*)d_in[4];
  const float* Wout = (const float*)d_in[5];
  const float* bout = (const float*)d_in[6];
  float* out = (float*)d_out;
  char* ws = (char*)d_ws;
  if (ws_size < 91358208u) return;  // workspace too small; fail loudly via wrong output

  unsigned short* wihb = (unsigned short*)(ws + 656384);
  unsigned short* whhb = (unsigned short*)(ws + 13239296);
  unsigned short* xb   = (unsigned short*)(ws + 25822208);

  // zero flags + h rings
  hipMemsetAsync(ws, 0, 656384, stream);
  prep_w<<<4096, 256, 0, stream>>>(Wih, Whh, wihb, whhb);
  prep_x<<<dim3(16, 32, 64), dim3(32, 8), 0, stream>>>(res, xb);
  gru_main<<<NWG, BLOCK, 0, stream>>>(xb, wihb, whhb, Wout, bih, bhh, bout, ws, out);
}